// Round 6
// baseline (331.420 us; speedup 1.0000x reference)
//
#include <hip/hip_runtime.h>

#define TPB 1024
#define NW (TPB / 64)
#define NCOLS 16384
#define NF4 (NCOLS / 4)          // 4096 float4 per row
#define F4PT (NF4 / TPB)         // 4 float4 per thread per row
#define BINS1 4096
#define SH1 19                   // key >> 19 -> 12-bit bin
#define CAP1 512                 // candidate capacity (expected E ~290)
#define GRID 256

typedef float f32x4 __attribute__((ext_vector_type(4)));
typedef __attribute__((address_space(1))) void void_g;
typedef __attribute__((address_space(3))) void void_l;

__device__ __forceinline__ unsigned keyOf(float f) {
    return __float_as_uint(f) & 0x7fffffffu;
}

// Issue async global->LDS copy of one row (64 KB) without touching VGPR data.
// LDS dest must be wave-uniform base + lane*16 (linear layout).
__device__ __forceinline__ void prefetch_row(const f32x4* __restrict__ grow,
                                             f32x4* lrow, int t) {
#pragma unroll
    for (int i = 0; i < F4PT; ++i) {
        const f32x4* g = grow + i * TPB + t;
        f32x4* l = lrow + i * TPB + (t & ~63);
        __builtin_amdgcn_global_load_lds((void_g*)g, (void_l*)l, 16, 0, 0);
    }
}

// Block-wide descending (suffix) select over hist[NBINS]: finds bin b s.t.
// sum(hist[b..NBINS-1]) first reaches >= Krem scanning from the top.
// bc[0]=cut bin, bc[1]=quota within bin, bc[2]=bin population.
template <int NBINS>
__device__ void suffix_select(const unsigned* hist, unsigned Krem,
                              unsigned* wsums, unsigned* bc) {
    const int t = threadIdx.x;
    const int lane = t & 63;
    const int wave = t >> 6;
    constexpr int CH = (NBINS + TPB - 1) / TPB;
    const int base = t * CH;
    unsigned c = 0;
#pragma unroll
    for (int i = 0; i < CH; ++i)
        if (base + i < NBINS) c += hist[base + i];
    unsigned s = c;   // in-wave inclusive suffix scan
#pragma unroll
    for (int off = 1; off < 64; off <<= 1) {
        unsigned o = __shfl_down(s, off);
        if (lane + off < 64) s += o;
    }
    if (lane == 0) wsums[wave] = s;
    __syncthreads();
    if (wave == 0) {
        unsigned ws = (lane < NW) ? wsums[lane] : 0u;
        unsigned ss = ws;
#pragma unroll
        for (int off = 1; off < NW; off <<= 1) {
            unsigned o = __shfl_down(ss, off);
            if (lane + off < NW) ss += o;
        }
        if (lane < NW) wsums[lane] = ss;
    }
    __syncthreads();
    unsigned gts = ((wave + 1 < NW) ? wsums[wave + 1] : 0u) + (s - c);
    if (gts < Krem && gts + c >= Krem) {  // exactly one thread brackets the cut
        unsigned cum = gts;
        for (int i = CH - 1; i >= 0; --i) {
            if (base + i >= NBINS) continue;
            unsigned h = hist[base + i];
            cum += h;
            if (cum >= Krem) {
                bc[0] = (unsigned)(base + i);
                bc[1] = Krem - (cum - h);
                bc[2] = h;
                break;
            }
        }
    }
    __syncthreads();
}

__global__ __launch_bounds__(TPB) void topk_mask_kernel(
        const float* __restrict__ x, const int* __restrict__ kp,
        float* __restrict__ out, int rpb) {
    __shared__ f32x4 rowbuf[2][NF4];          // 128 KB double-buffered row
    __shared__ unsigned hist[BINS1];          // 16 KB; overlaid after select
    __shared__ unsigned bitmap[NCOLS / 32];   // 2 KB keep-bits for tie class
    __shared__ unsigned wsums[NW];
    __shared__ unsigned bc[3];
    __shared__ unsigned cnt;

    unsigned* candKey = hist;                 // overlay (hist dead post-select)
    unsigned* candIdx = hist + CAP1;
    unsigned* hist2   = hist + 2 * CAP1;      // 256 bins, rare refine path

    const int t = threadIdx.x;
    const unsigned K = (unsigned)(*kp);
    const int row0 = blockIdx.x * rpb;
    const f32x4* xb = reinterpret_cast<const f32x4*>(x) + (size_t)row0 * NF4;
    f32x4* ob = reinterpret_cast<f32x4*>(out) + (size_t)row0 * NF4;

    prefetch_row(xb, rowbuf[0], t);           // prologue: row 0 in flight

    for (int k = 0; k < rpb; ++k) {
        f32x4* cur = rowbuf[k & 1];
        // 1. row k's prefetch (issued last iter) must have landed in LDS;
        //    also drains last iter's output stores.
        asm volatile("s_waitcnt vmcnt(0)" ::: "memory");
        __syncthreads();
        // 2. issue prefetch of row k+1 -> other buffer; stays in flight
        //    across ALL of this row's compute.
        if (k + 1 < rpb)
            prefetch_row(xb + (size_t)(k + 1) * NF4, rowbuf[(k + 1) & 1], t);

        // 3. zero hist/bitmap/cnt (stride-TPB: conflict-free)
#pragma unroll
        for (int i = 0; i < BINS1 / TPB; ++i) hist[t + i * TPB] = 0u;
        if (t < NCOLS / 32) bitmap[t] = 0u;
        if (t == 0) cnt = 0u;
        __syncthreads();

        // 4. 12-bit histogram from LDS
#pragma unroll
        for (int i = 0; i < F4PT; ++i) {
            f32x4 v = cur[t + i * TPB];
            atomicAdd(&hist[keyOf(v[0]) >> SH1], 1u);
            atomicAdd(&hist[keyOf(v[1]) >> SH1], 1u);
            atomicAdd(&hist[keyOf(v[2]) >> SH1], 1u);
            atomicAdd(&hist[keyOf(v[3]) >> SH1], 1u);
        }
        __syncthreads();
        suffix_select<BINS1>(hist, K, wsums, bc);
        unsigned p = bc[0];   // prefix value at shift s
        unsigned r = bc[1];   // quota among elements with (key>>s)==p
        unsigned E = bc[2];   // population of that class
        unsigned s = SH1;

        // 5. rare: refine prefix by 8 bits until class fits CAP1
        while (E > CAP1 && s > 0) {
            unsigned sh2 = (s >= 8) ? (s - 8) : 0u;
            unsigned width = s - sh2;
            unsigned mask = (1u << width) - 1u;
            if (t < 256) hist2[t] = 0u;
            __syncthreads();
#pragma unroll
            for (int i = 0; i < F4PT; ++i) {
                f32x4 v = cur[t + i * TPB];
#pragma unroll
                for (int j = 0; j < 4; ++j) {
                    unsigned key = keyOf(v[j]);
                    if ((key >> s) == p)
                        atomicAdd(&hist2[(key >> sh2) & mask], 1u);
                }
            }
            __syncthreads();
            suffix_select<256>(hist2, r, wsums, bc);
            p = (p << width) | bc[0];
            r = bc[1];
            E = bc[2];
            s = sh2;
        }

        const bool keepAll = (r == E);
        if (!keepAll) {
            // 6. compact candidate class from LDS, exact-rank it
#pragma unroll
            for (int i = 0; i < F4PT; ++i) {
                f32x4 v = cur[t + i * TPB];
#pragma unroll
                for (int j = 0; j < 4; ++j) {
                    unsigned key = keyOf(v[j]);
                    if ((key >> s) == p) {
                        unsigned idx = 4u * (unsigned)(t + i * TPB) + (unsigned)j;
                        unsigned pos = atomicAdd(&cnt, 1u);
                        if (pos < CAP1) { candKey[pos] = key; candIdx[pos] = idx; }
                    }
                }
            }
            __syncthreads();
            // rank: (key desc, idx asc) == jax top_k tie order; keep r best.
            // All lanes read the same q -> broadcast, conflict-free.
            unsigned m = (E < CAP1) ? E : CAP1;
            for (unsigned q0 = t; q0 < m; q0 += TPB) {
                unsigned k0 = candKey[q0], i0 = candIdx[q0], rank = 0;
                for (unsigned q = 0; q < m; ++q) {
                    unsigned kq = candKey[q];
                    rank += (kq > k0) || (kq == k0 && candIdx[q] < i0);
                }
                if (rank < r) atomicOr(&bitmap[i0 >> 5], 1u << (i0 & 31));
            }
            __syncthreads();
        }

        // 7. write masked row from LDS (nontemporal: write-once output)
        f32x4* orow = ob + (size_t)k * NF4;
#pragma unroll
        for (int i = 0; i < F4PT; ++i) {
            f32x4 v = cur[t + i * TPB];
            f32x4 o;
#pragma unroll
            for (int j = 0; j < 4; ++j) {
                float f = v[j];
                unsigned key = keyOf(f);
                unsigned b = key >> s;
                float of = 0.0f;
                if (b > p) {
                    of = f;
                } else if (b == p) {
                    unsigned idx = 4u * (unsigned)(t + i * TPB) + (unsigned)j;
                    if (keepAll || (((bitmap[idx >> 5] >> (idx & 31)) & 1u) != 0u))
                        of = f;
                }
                o[j] = of;
            }
            __builtin_nontemporal_store(o, &orow[t + i * TPB]);
        }
        // 8. protect hist/bitmap from next iter's zeroing while stragglers read
        __syncthreads();
    }
}

extern "C" void kernel_launch(void* const* d_in, const int* in_sizes, int n_in,
                              void* d_out, int out_size, void* d_ws, size_t ws_size,
                              hipStream_t stream) {
    const float* x = (const float*)d_in[0];
    const int* kp = (const int*)d_in[1];
    float* out = (float*)d_out;
    const int rows = in_sizes[0] / NCOLS;   // 4096
    const int rpb = rows / GRID;            // 16 rows per persistent block
    topk_mask_kernel<<<GRID, TPB, 0, stream>>>(x, kp, out, rpb);
}

// Round 7
// 320.125 us; speedup vs baseline: 1.0353x; 1.0353x over previous
//
#include <hip/hip_runtime.h>

#define TPB 512
#define NW (TPB / 64)            // 8 waves
#define NCOLS 16384
#define NF4 (NCOLS / 4)          // 4096 float4 per row
#define F4PT (NF4 / TPB)         // 8 float4 per thread
#define BINS 2048
#define SH 20                    // key >> 20 -> 11-bit bin (8 exp + 3 mant)
#define CAP 512                  // candidate capacity (expected E ~350)

typedef float f32x4 __attribute__((ext_vector_type(4)));

__device__ __forceinline__ unsigned keyOf(float f) {
    return __float_as_uint(f) & 0x7fffffffu;
}

// Block-wide descending (suffix) select over hist[NBINS]: finds bin b s.t.
// sum(hist[b..NBINS-1]) first reaches >= Krem scanning from the top.
// bc[0]=cut bin, bc[1]=quota within bin, bc[2]=bin population.
template <int NBINS>
__device__ void suffix_select(const unsigned* hist, unsigned Krem,
                              unsigned* wsums, unsigned* bc) {
    const int t = threadIdx.x;
    const int lane = t & 63;
    const int wave = t >> 6;
    constexpr int CH = (NBINS + TPB - 1) / TPB;
    const int base = t * CH;
    unsigned c = 0;
#pragma unroll
    for (int i = 0; i < CH; ++i)
        if (base + i < NBINS) c += hist[base + i];
    unsigned s = c;   // in-wave inclusive suffix scan
#pragma unroll
    for (int off = 1; off < 64; off <<= 1) {
        unsigned o = __shfl_down(s, off);
        if (lane + off < 64) s += o;
    }
    if (lane == 0) wsums[wave] = s;
    __syncthreads();
    if (wave == 0) {
        unsigned ws = (lane < NW) ? wsums[lane] : 0u;
        unsigned ss = ws;
#pragma unroll
        for (int off = 1; off < NW; off <<= 1) {
            unsigned o = __shfl_down(ss, off);
            if (lane + off < NW) ss += o;
        }
        if (lane < NW) wsums[lane] = ss;
    }
    __syncthreads();
    unsigned gts = ((wave + 1 < NW) ? wsums[wave + 1] : 0u) + (s - c);
    if (gts < Krem && gts + c >= Krem) {  // exactly one thread brackets the cut
        unsigned cum = gts;
        for (int i = CH - 1; i >= 0; --i) {
            if (base + i >= NBINS) continue;
            unsigned h = hist[base + i];
            cum += h;
            if (cum >= Krem) {
                bc[0] = (unsigned)(base + i);
                bc[1] = Krem - (cum - h);
                bc[2] = h;
                break;
            }
        }
    }
    __syncthreads();
}

__global__ __launch_bounds__(TPB, 4) void topk_mask_kernel(
        const float* __restrict__ x, const int* __restrict__ kp,
        float* __restrict__ out) {
    __shared__ f32x4 lrow[NF4];               // 64 KB: the staged row
    __shared__ unsigned hist[BINS];           // 8 KB
    __shared__ unsigned candKey[CAP];         // 2 KB
    __shared__ unsigned candIdx[CAP];         // 2 KB
    __shared__ unsigned wsums[NW];
    __shared__ unsigned bc[3];
    __shared__ unsigned cnt;

    const int t = threadIdx.x;
    const unsigned K = (unsigned)(*kp);
    const f32x4* xr =
        reinterpret_cast<const f32x4*>(x) + (size_t)blockIdx.x * NF4;
    f32x4* orow =
        reinterpret_cast<f32x4*>(out) + (size_t)blockIdx.x * NF4;
    float* lf = reinterpret_cast<float*>(lrow);

    // zero hist + cnt (stride-TPB: conflict-free)
#pragma unroll
    for (int i = 0; i < BINS / TPB; ++i) hist[t + i * TPB] = 0u;
    if (t == 0) cnt = 0u;
    __syncthreads();

    // ---------- P1: single global read; stage row to LDS + histogram ----------
#pragma unroll
    for (int i = 0; i < F4PT; ++i) {
        f32x4 v = xr[t + i * TPB];
        lrow[t + i * TPB] = v;
        atomicAdd(&hist[keyOf(v[0]) >> SH], 1u);
        atomicAdd(&hist[keyOf(v[1]) >> SH], 1u);
        atomicAdd(&hist[keyOf(v[2]) >> SH], 1u);
        atomicAdd(&hist[keyOf(v[3]) >> SH], 1u);
    }
    __syncthreads();
    suffix_select<BINS>(hist, K, wsums, bc);
    unsigned p = bc[0];   // prefix value at shift s
    unsigned r = bc[1];   // quota among elements with (key>>s)==p
    unsigned E = bc[2];   // population of that class
    unsigned s = SH;

    // ---------- rare: refine prefix by 8 bits until class fits CAP ----------
    while (E > CAP && s > 0) {
        unsigned sh2 = (s >= 8) ? (s - 8) : 0u;
        unsigned width = s - sh2;
        unsigned mask = (1u << width) - 1u;
        if (t < 256) hist[t] = 0u;
        __syncthreads();
#pragma unroll
        for (int i = 0; i < F4PT; ++i) {
            f32x4 v = lrow[t + i * TPB];
#pragma unroll
            for (int j = 0; j < 4; ++j) {
                unsigned key = keyOf(v[j]);
                if ((key >> s) == p) atomicAdd(&hist[(key >> sh2) & mask], 1u);
            }
        }
        __syncthreads();
        suffix_select<256>(hist, r, wsums, bc);
        p = (p << width) | bc[0];
        r = bc[1];
        E = bc[2];
        s = sh2;
    }

    if (r < E) {
        if (E <= CAP) {
            // ---- compact tie class from LDS, rank, zero dropped in lrow ----
#pragma unroll
            for (int i = 0; i < F4PT; ++i) {
                f32x4 v = lrow[t + i * TPB];
#pragma unroll
                for (int j = 0; j < 4; ++j) {
                    unsigned key = keyOf(v[j]);
                    if ((key >> s) == p) {
                        unsigned idx = 4u * (unsigned)(t + i * TPB) + (unsigned)j;
                        unsigned pos = atomicAdd(&cnt, 1u);
                        candKey[pos] = key;
                        candIdx[pos] = idx;
                    }
                }
            }
            __syncthreads();
            // rank: (key desc, idx asc) == jax top_k tie order; drop rank>=r.
            // Broadcast LDS reads over q -> conflict-free.
            for (unsigned q0 = t; q0 < E; q0 += TPB) {
                unsigned k0 = candKey[q0], i0 = candIdx[q0], rank = 0;
                for (unsigned q = 0; q < E; ++q) {
                    unsigned kq = candKey[q];
                    rank += (kq > k0) || (kq == k0 && candIdx[q] < i0);
                }
                if (rank >= r) lf[i0] = 0.0f;   // dropped: key->0 < p
            }
            __syncthreads();
        } else {
            // ---- s==0, huge exact-key class: keep r lowest indices.
            // Index-reversed histogram + suffix_select == prefix select.
#pragma unroll
            for (int i = 0; i < BINS / TPB; ++i) hist[t + i * TPB] = 0u;
            __syncthreads();
#pragma unroll
            for (int i = 0; i < F4PT; ++i) {
                f32x4 v = lrow[t + i * TPB];
#pragma unroll
                for (int j = 0; j < 4; ++j) {
                    if (keyOf(v[j]) == p) {
                        unsigned idx = 4u * (unsigned)(t + i * TPB) + (unsigned)j;
                        atomicAdd(&hist[(BINS - 1) - (idx >> 3)], 1u);
                    }
                }
            }
            __syncthreads();
            suffix_select<BINS>(hist, r, wsums, bc);
            unsigned gstar = (BINS - 1) - bc[0];  // cut index-group
            unsigned rg = bc[1];                  // quota within that group
            // Phase A: decide keep-bit per element (no LDS writes yet)
            unsigned keepMask[F4PT];
#pragma unroll
            for (int i = 0; i < F4PT; ++i) {
                f32x4 v = lrow[t + i * TPB];
                keepMask[i] = 0u;
#pragma unroll
                for (int j = 0; j < 4; ++j) {
                    if (keyOf(v[j]) == p) {
                        unsigned idx = 4u * (unsigned)(t + i * TPB) + (unsigned)j;
                        unsigned g = idx >> 3;
                        bool keep = false;
                        if (g < gstar) keep = true;
                        else if (g == gstar) {
                            unsigned before = 0;  // matches in group, smaller idx
                            for (unsigned c = g << 3; c < idx; ++c)
                                before += (keyOf(lf[c]) == p);
                            keep = (before < rg);
                        }
                        if (keep) keepMask[i] |= (1u << j);
                    }
                }
            }
            __syncthreads();
            // Phase B: zero dropped
#pragma unroll
            for (int i = 0; i < F4PT; ++i) {
                f32x4 v = lrow[t + i * TPB];
#pragma unroll
                for (int j = 0; j < 4; ++j) {
                    if (keyOf(v[j]) == p && !((keepMask[i] >> j) & 1u)) {
                        unsigned idx = 4u * (unsigned)(t + i * TPB) + (unsigned)j;
                        lf[idx] = 0.0f;
                    }
                }
            }
            __syncthreads();
        }
    }

    // ---------- write pass from LDS (nontemporal: write-once output) ----------
#pragma unroll
    for (int i = 0; i < F4PT; ++i) {
        f32x4 v = lrow[t + i * TPB];
        f32x4 o;
#pragma unroll
        for (int j = 0; j < 4; ++j)
            o[j] = ((keyOf(v[j]) >> s) >= p) ? v[j] : 0.0f;
        __builtin_nontemporal_store(o, &orow[t + i * TPB]);
    }
}

extern "C" void kernel_launch(void* const* d_in, const int* in_sizes, int n_in,
                              void* d_out, int out_size, void* d_ws, size_t ws_size,
                              hipStream_t stream) {
    const float* x = (const float*)d_in[0];
    const int* kp = (const int*)d_in[1];
    float* out = (float*)d_out;
    const int rows = in_sizes[0] / NCOLS;   // 4096
    topk_mask_kernel<<<rows, TPB, 0, stream>>>(x, kp, out);
}

// Round 8
// 186.241 us; speedup vs baseline: 1.7795x; 1.7189x over previous
//
#include <hip/hip_runtime.h>

#define TPB 1024
#define NW (TPB / 64)           // 16 waves
#define NCOLS 16384
#define NF4 (NCOLS / 4)         // 4096 float4 per row
#define F4PT (NF4 / TPB)        // 4 float4 per thread
#define BINS 8192
#define SH 18                   // key >> 18 -> 13-bit bin
#define CAP 512                 // cut-class capacity (expected E ~145)
#define GRID 256

typedef float f32x4 __attribute__((ext_vector_type(4)));

__device__ __forceinline__ unsigned keyOf(float f) {
    return __float_as_uint(f) & 0x7fffffffu;
}

struct Shm {
    unsigned hist[BINS];     // 32 KB
    unsigned candKey[CAP];   // 2 KB
    unsigned candIdx[CAP];   // 2 KB
    unsigned rankOf[CAP];    // 2 KB
    unsigned wsums[NW];
    unsigned bc[3];
    unsigned cnt;
    unsigned thi, tlo;       // packed threshold: thi=key, tlo=16383-idx
};

// Block-wide descending (suffix) select over hist[NBINS]: finds bin b s.t.
// sum(hist[b..NBINS-1]) first reaches >= Krem scanning from the top.
// bc[0]=cut bin, bc[1]=quota within bin, bc[2]=bin population.
template <int NBINS>
__device__ void suffix_select(const unsigned* hist, unsigned Krem,
                              unsigned* wsums, unsigned* bc) {
    const int t = threadIdx.x;
    const int lane = t & 63;
    const int wave = t >> 6;
    constexpr int CH = (NBINS + TPB - 1) / TPB;
    const int base = t * CH;
    unsigned c = 0;
#pragma unroll
    for (int i = 0; i < CH; ++i)
        if (base + i < NBINS) c += hist[base + i];
    unsigned s = c;   // in-wave inclusive suffix scan
#pragma unroll
    for (int off = 1; off < 64; off <<= 1) {
        unsigned o = __shfl_down(s, off);
        if (lane + off < 64) s += o;
    }
    if (lane == 0) wsums[wave] = s;
    __syncthreads();
    if (wave == 0) {
        unsigned ws = (lane < NW) ? wsums[lane] : 0u;
        unsigned ss = ws;
#pragma unroll
        for (int off = 1; off < NW; off <<= 1) {
            unsigned o = __shfl_down(ss, off);
            if (lane + off < NW) ss += o;
        }
        if (lane < NW) wsums[lane] = ss;
    }
    __syncthreads();
    unsigned gts = ((wave + 1 < NW) ? wsums[wave + 1] : 0u) + (s - c);
    if (gts < Krem && gts + c >= Krem) {  // exactly one thread brackets the cut
        unsigned cum = gts;
        for (int i = CH - 1; i >= 0; --i) {
            if (base + i >= NBINS) continue;
            unsigned h = hist[base + i];
            cum += h;
            if (cum >= Krem) {
                bc[0] = (unsigned)(base + i);
                bc[1] = Krem - (cum - h);
                bc[2] = h;
                break;
            }
        }
    }
    __syncthreads();
}

__device__ __forceinline__ void process_row(
        f32x4 (&cur)[F4PT], f32x4 (&nxt)[F4PT],
        const f32x4* __restrict__ nxt_src, bool do_prefetch,
        f32x4* __restrict__ orow, unsigned K, Shm& sh) {
    const int t = threadIdx.x;

    // Issue next row's loads into registers FIRST: latency hides under this
    // row's compute; register loads do NOT force vmcnt drain at barriers.
    if (do_prefetch) {
#pragma unroll
        for (int i = 0; i < F4PT; ++i) nxt[i] = nxt_src[t + i * TPB];
    }

    // zero hist + cnt (stride-TPB: conflict-free)
#pragma unroll
    for (int i = 0; i < BINS / TPB; ++i) sh.hist[t + i * TPB] = 0u;
    if (t == 0) sh.cnt = 0u;
    __syncthreads();

    // ---------- 13-bit histogram from registers ----------
#pragma unroll
    for (int i = 0; i < F4PT; ++i) {
#pragma unroll
        for (int j = 0; j < 4; ++j)
            atomicAdd(&sh.hist[keyOf(cur[i][j]) >> SH], 1u);
    }
    __syncthreads();
    suffix_select<BINS>(sh.hist, K, sh.wsums, sh.bc);
    unsigned p = sh.bc[0];   // class prefix at shift s
    unsigned r = sh.bc[1];   // quota within class (>=1)
    unsigned E = sh.bc[2];   // class population
    unsigned s = SH;

    // ---------- rare: refine class by 8 bits until it fits CAP ----------
    while (E > CAP && s > 0) {
        unsigned sh2 = (s >= 8) ? (s - 8) : 0u;
        unsigned width = s - sh2;
        unsigned mask = (1u << width) - 1u;
        if (t < 256) sh.hist[t] = 0u;
        __syncthreads();
#pragma unroll
        for (int i = 0; i < F4PT; ++i) {
#pragma unroll
            for (int j = 0; j < 4; ++j) {
                unsigned key = keyOf(cur[i][j]);
                if ((key >> s) == p) atomicAdd(&sh.hist[(key >> sh2) & mask], 1u);
            }
        }
        __syncthreads();
        suffix_select<256>(sh.hist, r, sh.wsums, sh.bc);
        p = (p << width) | sh.bc[0];
        r = sh.bc[1];
        E = sh.bc[2];
        s = sh2;
    }

    if (E <= CAP) {
        // ---------- compact class from registers; exact rank ----------
#pragma unroll
        for (int i = 0; i < F4PT; ++i) {
#pragma unroll
            for (int j = 0; j < 4; ++j) {
                unsigned key = keyOf(cur[i][j]);
                if ((key >> s) == p) {
                    unsigned idx = 4u * (unsigned)(t + i * TPB) + (unsigned)j;
                    unsigned pos = atomicAdd(&sh.cnt, 1u);
                    sh.candKey[pos] = key;
                    sh.candIdx[pos] = idx;
                }
            }
        }
        if (t < CAP) sh.rankOf[t] = 0u;
        __syncthreads();
        // 2-way split rank: (key desc, idx asc) == jax top_k tie order.
        // Broadcast LDS reads over qq -> conflict-free.
        unsigned q = (unsigned)t & (CAP - 1);
        unsigned half = (unsigned)t >> 9;
        if (q < E) {
            unsigned k0 = sh.candKey[q], i0 = sh.candIdx[q];
            unsigned lo = half ? (E >> 1) : 0u;
            unsigned hi = half ? E : (E >> 1);
            unsigned part = 0;
            for (unsigned qq = lo; qq < hi; ++qq) {
                unsigned kq = sh.candKey[qq];
                part += (kq > k0) || (kq == k0 && sh.candIdx[qq] < i0);
            }
            if (part) atomicAdd(&sh.rankOf[q], part);
        }
        __syncthreads();
        if ((unsigned)t < E && sh.rankOf[t] == r - 1) {  // unique: K-th largest
            sh.thi = sh.candKey[t];
            sh.tlo = 16383u - sh.candIdx[t];
        }
        __syncthreads();
    } else {
        // ---------- pathological: s==0, huge exact-key class ----------
        // Keep r lowest indices: reversed-index histogram over f=idx>>2.
#pragma unroll
        for (int i = 0; i < 4096 / TPB; ++i) sh.hist[t + i * TPB] = 0u;
        __syncthreads();
#pragma unroll
        for (int i = 0; i < F4PT; ++i) {
#pragma unroll
            for (int j = 0; j < 4; ++j) {
                if (keyOf(cur[i][j]) == p) {
                    unsigned f = (unsigned)(t + i * TPB);
                    atomicAdd(&sh.hist[4095u - f], 1u);
                }
            }
        }
        __syncthreads();
        suffix_select<4096>(sh.hist, r, sh.wsums, sh.bc);
        unsigned gstar = 4095u - sh.bc[0];   // cut float4-group
        unsigned rg = sh.bc[1];              // quota within that group
        if ((unsigned)t == (gstar & 1023u)) {
            unsigned estar = gstar >> 10;
#pragma unroll
            for (int i = 0; i < F4PT; ++i) {
                if ((unsigned)i == estar) {
                    unsigned seen = 0;
#pragma unroll
                    for (int j = 0; j < 4; ++j) {
                        if (keyOf(cur[i][j]) == p) {
                            ++seen;
                            if (seen == rg) {
                                unsigned idx = 4u * gstar + (unsigned)j;
                                sh.thi = p;
                                sh.tlo = 16383u - idx;
                            }
                        }
                    }
                }
            }
        }
        __syncthreads();
    }

    // ---------- masked write: pure packed-threshold compare ----------
    const unsigned Tkey = sh.thi, Tlo = sh.tlo;
#pragma unroll
    for (int i = 0; i < F4PT; ++i) {
        f32x4 o;
#pragma unroll
        for (int j = 0; j < 4; ++j) {
            float f = cur[i][j];
            unsigned key = keyOf(f);
            unsigned idx = 4u * (unsigned)(t + i * TPB) + (unsigned)j;
            bool keep = (key > Tkey) || (key == Tkey && (16383u - idx) >= Tlo);
            o[j] = keep ? f : 0.0f;
        }
        __builtin_nontemporal_store(o, &orow[t + i * TPB]);
    }
    // No trailing barrier: next row's zero+barrier protects hist; thi/tlo
    // were read above, and their next write is behind multiple barriers.
}

__global__ __launch_bounds__(TPB) void topk_mask_kernel(
        const float* __restrict__ x, const int* __restrict__ kp,
        float* __restrict__ out, int rpb) {
    __shared__ Shm sh;
    const int t = threadIdx.x;
    const unsigned K = (unsigned)(*kp);
    const size_t row0 = (size_t)blockIdx.x * rpb;
    const f32x4* xb = reinterpret_cast<const f32x4*>(x) + row0 * NF4;
    f32x4* ob = reinterpret_cast<f32x4*>(out) + row0 * NF4;

    f32x4 A[F4PT], B[F4PT];
#pragma unroll
    for (int i = 0; i < F4PT; ++i) A[i] = xb[t + i * TPB];

    int k = 0;
    for (; k + 1 < rpb; k += 2) {
        process_row(A, B, xb + (size_t)(k + 1) * NF4, true,
                    ob + (size_t)k * NF4, K, sh);
        process_row(B, A, xb + (size_t)(k + 2) * NF4, k + 2 < rpb,
                    ob + (size_t)(k + 1) * NF4, K, sh);
    }
    if (k < rpb) {   // odd tail (unused at 4096/256 but kept general)
        process_row(A, B, xb, false, ob + (size_t)k * NF4, K, sh);
    }
}

extern "C" void kernel_launch(void* const* d_in, const int* in_sizes, int n_in,
                              void* d_out, int out_size, void* d_ws, size_t ws_size,
                              hipStream_t stream) {
    const float* x = (const float*)d_in[0];
    const int* kp = (const int*)d_in[1];
    float* out = (float*)d_out;
    const int rows = in_sizes[0] / NCOLS;   // 4096
    const int rpb = rows / GRID;            // 16 rows per persistent block
    topk_mask_kernel<<<GRID, TPB, 0, stream>>>(x, kp, out, rpb);
}

// Round 9
// 176.554 us; speedup vs baseline: 1.8772x; 1.0549x over previous
//
#include <hip/hip_runtime.h>

#define TPB 1024
#define NW (TPB / 64)           // 16 waves
#define NCOLS 16384
#define NF4 (NCOLS / 4)         // 4096 float4 per row
#define F4PT (NF4 / TPB)        // 4 float4 per thread
#define BINS 8192
#define SH 18                   // key >> 18 -> 13-bit bin
#define CAP 512                 // cut-class capacity (expected E ~145)
#define GRID 256

typedef float f32x4 __attribute__((ext_vector_type(4)));

__device__ __forceinline__ unsigned keyOf(float f) {
    return __float_as_uint(f) & 0x7fffffffu;
}

// LDS-only barrier: waits DS ops, leaves global loads/stores (vmcnt) in
// flight. Legal here because ALL block-internal communication is via LDS.
// (__syncthreads would emit s_waitcnt vmcnt(0) and kill the row prefetch.)
#define BAR() asm volatile("s_waitcnt lgkmcnt(0)\n\ts_barrier" ::: "memory")

// Interleaved histogram address: bin b -> (b>>IL) | ((b&(2^IL-1)) << (LOG-IL)).
// Thread t's CH-contiguous chunk then reads lane-consecutive words
// (conflict-free) in suffix_select, while atomic updates stay spread.
template <int NBINS, int IL>
__device__ __forceinline__ unsigned histAddr(unsigned b) {
    constexpr unsigned LOG = (unsigned)(__builtin_ctz(NBINS));
    return (b >> IL) | ((b & ((1u << IL) - 1u)) << (LOG - (unsigned)IL));
}

struct Shm {
    unsigned hist[BINS];     // 32 KB
    unsigned candKey[CAP];   // 2 KB
    unsigned candIdx[CAP];   // 2 KB
    unsigned rankOf[CAP];    // 2 KB
    unsigned wsums[NW];
    unsigned bc[3];
    unsigned cnt;
    unsigned thi, tlo;       // packed threshold: thi=key, tlo=16383-idx
};

// Block-wide descending (suffix) select over hist[NBINS] (stored via
// histAddr<NBINS,IL>): finds bin b s.t. sum(hist[b..NBINS-1]) >= Krem first,
// scanning from the top. bc[0]=cut bin, bc[1]=quota, bc[2]=bin population.
template <int NBINS, int IL>
__device__ void suffix_select(const unsigned* hist, unsigned Krem,
                              unsigned* wsums, unsigned* bc) {
    const int t = threadIdx.x;
    const int lane = t & 63;
    const int wave = t >> 6;
    constexpr int CH = (NBINS + TPB - 1) / TPB;
    const int base = t * CH;
    unsigned c = 0;
#pragma unroll
    for (int i = 0; i < CH; ++i)
        if (base + i < NBINS) c += hist[histAddr<NBINS, IL>(base + i)];
    unsigned s = c;   // in-wave inclusive suffix scan
#pragma unroll
    for (int off = 1; off < 64; off <<= 1) {
        unsigned o = __shfl_down(s, off);
        if (lane + off < 64) s += o;
    }
    if (lane == 0) wsums[wave] = s;
    BAR();
    if (wave == 0) {
        unsigned ws = (lane < NW) ? wsums[lane] : 0u;
        unsigned ss = ws;
#pragma unroll
        for (int off = 1; off < NW; off <<= 1) {
            unsigned o = __shfl_down(ss, off);
            if (lane + off < NW) ss += o;
        }
        if (lane < NW) wsums[lane] = ss;
    }
    BAR();
    unsigned gts = ((wave + 1 < NW) ? wsums[wave + 1] : 0u) + (s - c);
    if (gts < Krem && gts + c >= Krem) {  // exactly one thread brackets the cut
        unsigned cum = gts;
        for (int i = CH - 1; i >= 0; --i) {
            if (base + i >= NBINS) continue;
            unsigned h = hist[histAddr<NBINS, IL>(base + i)];
            cum += h;
            if (cum >= Krem) {
                bc[0] = (unsigned)(base + i);
                bc[1] = Krem - (cum - h);
                bc[2] = h;
                break;
            }
        }
    }
    BAR();
}

__device__ __forceinline__ void process_row(
        f32x4 (&cur)[F4PT], f32x4 (&nxt)[F4PT],
        const f32x4* __restrict__ nxt_src, bool do_prefetch,
        f32x4* __restrict__ orow, unsigned K, Shm& sh) {
    const int t = threadIdx.x;

    // Issue next row's loads FIRST; LDS-only barriers below never drain
    // vmcnt, so these stay in flight across this entire row's compute.
    if (do_prefetch) {
#pragma unroll
        for (int i = 0; i < F4PT; ++i) nxt[i] = nxt_src[t + i * TPB];
    }

    // zero hist + cnt (stride-TPB raw addresses: conflict-free)
#pragma unroll
    for (int i = 0; i < BINS / TPB; ++i) sh.hist[t + i * TPB] = 0u;
    if (t == 0) sh.cnt = 0u;
    BAR();

    // ---------- 13-bit histogram from registers ----------
#pragma unroll
    for (int i = 0; i < F4PT; ++i) {
#pragma unroll
        for (int j = 0; j < 4; ++j)
            atomicAdd(&sh.hist[histAddr<BINS, 3>(keyOf(cur[i][j]) >> SH)], 1u);
    }
    BAR();
    suffix_select<BINS, 3>(sh.hist, K, sh.wsums, sh.bc);
    unsigned p = sh.bc[0];   // class prefix at shift s
    unsigned r = sh.bc[1];   // quota within class (>=1)
    unsigned E = sh.bc[2];   // class population
    unsigned s = SH;

    // ---------- rare: refine class by 8 bits until it fits CAP ----------
    while (E > CAP && s > 0) {
        unsigned sh2 = (s >= 8) ? (s - 8) : 0u;
        unsigned width = s - sh2;
        unsigned mask = (1u << width) - 1u;
        if (t < 256) sh.hist[t] = 0u;
        BAR();
#pragma unroll
        for (int i = 0; i < F4PT; ++i) {
#pragma unroll
            for (int j = 0; j < 4; ++j) {
                unsigned key = keyOf(cur[i][j]);
                if ((key >> s) == p) atomicAdd(&sh.hist[(key >> sh2) & mask], 1u);
            }
        }
        BAR();
        suffix_select<256, 0>(sh.hist, r, sh.wsums, sh.bc);
        p = (p << width) | sh.bc[0];
        r = sh.bc[1];
        E = sh.bc[2];
        s = sh2;
    }

    if (E <= CAP) {
        // ---------- compact class from registers; exact rank ----------
#pragma unroll
        for (int i = 0; i < F4PT; ++i) {
#pragma unroll
            for (int j = 0; j < 4; ++j) {
                unsigned key = keyOf(cur[i][j]);
                if ((key >> s) == p) {
                    unsigned idx = 4u * (unsigned)(t + i * TPB) + (unsigned)j;
                    unsigned pos = atomicAdd(&sh.cnt, 1u);
                    sh.candKey[pos] = key;
                    sh.candIdx[pos] = idx;
                }
            }
        }
        if (t < CAP) sh.rankOf[t] = 0u;
        BAR();
        // 2-way split rank: (key desc, idx asc) == jax top_k tie order.
        // Broadcast LDS reads over qq -> conflict-free.
        unsigned q = (unsigned)t & (CAP - 1);
        unsigned half = (unsigned)t >> 9;
        if (q < E) {
            unsigned k0 = sh.candKey[q], i0 = sh.candIdx[q];
            unsigned lo = half ? (E >> 1) : 0u;
            unsigned hi = half ? E : (E >> 1);
            unsigned part = 0;
            for (unsigned qq = lo; qq < hi; ++qq) {
                unsigned kq = sh.candKey[qq];
                part += (kq > k0) || (kq == k0 && sh.candIdx[qq] < i0);
            }
            if (part) atomicAdd(&sh.rankOf[q], part);
        }
        BAR();
        if ((unsigned)t < E && sh.rankOf[t] == r - 1) {  // unique: K-th largest
            sh.thi = sh.candKey[t];
            sh.tlo = 16383u - sh.candIdx[t];
        }
        BAR();
    } else {
        // ---------- pathological: s==0, huge exact-key class ----------
        // Keep r lowest indices: reversed-index histogram over f4-groups.
#pragma unroll
        for (int i = 0; i < 4096 / TPB; ++i) sh.hist[t + i * TPB] = 0u;
        BAR();
#pragma unroll
        for (int i = 0; i < F4PT; ++i) {
#pragma unroll
            for (int j = 0; j < 4; ++j) {
                if (keyOf(cur[i][j]) == p) {
                    unsigned f = (unsigned)(t + i * TPB);
                    atomicAdd(&sh.hist[histAddr<4096, 2>(4095u - f)], 1u);
                }
            }
        }
        BAR();
        suffix_select<4096, 2>(sh.hist, r, sh.wsums, sh.bc);
        unsigned gstar = 4095u - sh.bc[0];   // cut float4-group
        unsigned rg = sh.bc[1];              // quota within that group
        if ((unsigned)t == (gstar & 1023u)) {
            unsigned estar = gstar >> 10;
#pragma unroll
            for (int i = 0; i < F4PT; ++i) {
                if ((unsigned)i == estar) {
                    unsigned seen = 0;
#pragma unroll
                    for (int j = 0; j < 4; ++j) {
                        if (keyOf(cur[i][j]) == p) {
                            ++seen;
                            if (seen == rg) {
                                unsigned idx = 4u * gstar + (unsigned)j;
                                sh.thi = p;
                                sh.tlo = 16383u - idx;
                            }
                        }
                    }
                }
            }
        }
        BAR();
    }

    // ---------- masked write: pure packed-threshold compare ----------
    const unsigned Tkey = sh.thi, Tlo = sh.tlo;
#pragma unroll
    for (int i = 0; i < F4PT; ++i) {
        f32x4 o;
#pragma unroll
        for (int j = 0; j < 4; ++j) {
            float f = cur[i][j];
            unsigned key = keyOf(f);
            unsigned idx = 4u * (unsigned)(t + i * TPB) + (unsigned)j;
            bool keep = (key > Tkey) || (key == Tkey && (16383u - idx) >= Tlo);
            o[j] = keep ? f : 0.0f;
        }
        __builtin_nontemporal_store(o, &orow[t + i * TPB]);
    }
    // No trailing barrier needed: next row's first BAR (after hist zeroing)
    // stalls fast waves before any shared state this row still reads is
    // overwritten (thi/tlo rewritten only after 3+ barriers in row k+1).
}

__global__ __launch_bounds__(TPB, 4) void topk_mask_kernel(
        const float* __restrict__ x, const int* __restrict__ kp,
        float* __restrict__ out, int rpb) {
    __shared__ Shm sh;
    const int t = threadIdx.x;
    const unsigned K = (unsigned)(*kp);
    const size_t row0 = (size_t)blockIdx.x * rpb;
    const f32x4* xb = reinterpret_cast<const f32x4*>(x) + row0 * NF4;
    f32x4* ob = reinterpret_cast<f32x4*>(out) + row0 * NF4;

    f32x4 A[F4PT], B[F4PT];
#pragma unroll
    for (int i = 0; i < F4PT; ++i) A[i] = xb[t + i * TPB];

    int k = 0;
    for (; k + 1 < rpb; k += 2) {
        process_row(A, B, xb + (size_t)(k + 1) * NF4, true,
                    ob + (size_t)k * NF4, K, sh);
        process_row(B, A, xb + (size_t)(k + 2) * NF4, k + 2 < rpb,
                    ob + (size_t)(k + 1) * NF4, K, sh);
    }
    if (k < rpb) {   // odd tail (unused at 4096/256 but kept general)
        process_row(A, B, xb, false, ob + (size_t)k * NF4, K, sh);
    }
}

extern "C" void kernel_launch(void* const* d_in, const int* in_sizes, int n_in,
                              void* d_out, int out_size, void* d_ws, size_t ws_size,
                              hipStream_t stream) {
    const float* x = (const float*)d_in[0];
    const int* kp = (const int*)d_in[1];
    float* out = (float*)d_out;
    const int rows = in_sizes[0] / NCOLS;   // 4096
    const int rpb = rows / GRID;            // 16 rows per persistent block
    topk_mask_kernel<<<GRID, TPB, 0, stream>>>(x, kp, out, rpb);
}